// Round 6
// baseline (456.874 us; speedup 1.0000x reference)
//
#include <hip/hip_runtime.h>

#define NE 11
#define NP 64
#define NC 128
#define NHW 4096
#define NHID 512

typedef __attribute__((ext_vector_type(8))) __bf16 bf16x8;
typedef __attribute__((ext_vector_type(4))) __bf16 bf16x4;
typedef __attribute__((ext_vector_type(4))) float f32x4;

#if __has_builtin(__builtin_amdgcn_exp2f)
#define FEXP2(x) __builtin_amdgcn_exp2f(x)
#else
#define FEXP2(x) exp2f(x)
#endif
#if __has_builtin(__builtin_amdgcn_rcpf)
#define FRCP(x) __builtin_amdgcn_rcpf(x)
#else
#define FRCP(x) (1.0f / (x))
#endif

__device__ __forceinline__ unsigned short f2bf(float f) {
    return __builtin_bit_cast(unsigned short, (__bf16)f);
}

// Exact-to-1.5e-7 gelu via A&S 7.1.26 erf polynomial, branchless.
// gelu(v) = 0.5 v (1 + erf(v/sqrt2)); uses gelu(v) = gelu(|v|) + min(v,0).
__device__ __forceinline__ float gelu_erf(float v) {
    float av = fabsf(v);
    float z = av * 0.70710678118654752440f;
    float t = FRCP(fmaf(z, 0.3275911f, 1.0f));
    float p = t * fmaf(t, fmaf(t, fmaf(t, fmaf(t, 1.061405429f, -1.453152027f),
                                       1.421413741f), -0.284496736f), 0.254829592f);
    float e = FEXP2(z * z * -1.44269504088896f); // exp(-z^2)
    float erfz = fmaf(-p, e, 1.0f);              // erf(z), z>=0
    float hv = 0.5f * av;
    float g = fmaf(hv, erfz, hv);                // gelu(|v|)
    return g + fminf(v, 0.0f);
}

// LDS B-fragment read: row-major [row][128] bf16 tile, XOR-swizzled
__device__ __forceinline__ bf16x8 ldsB(const char* base, int row, int col) {
    int off = ((row << 8) + (col << 1)) ^ ((row & 7) << 4);
    return *(const bf16x8*)(base + off);
}

// ---------------- kernel 1: weight cvt (blocks 0-511) + global pool (512-1535) ----------------
__global__ void k_prep(const float* __restrict__ ew1, const float* __restrict__ ew2,
                       unsigned short* __restrict__ o1, unsigned short* __restrict__ o2,
                       const float* __restrict__ x, float* __restrict__ gc) {
    if (blockIdx.x < 512) {
        const int n = NE * NHID * NC;
        for (int i = blockIdx.x * 256 + threadIdx.x; i < n; i += 512 * 256) {
            o1[i] = f2bf(ew1[i]);
            o2[i] = f2bf(ew2[i]);
        }
    } else {
        int row = blockIdx.x - 512; // b*128+c
        const float* p = x + (size_t)row * NHW;
        float s = 0.f;
        for (int i = threadIdx.x; i < NHW; i += 256) s += p[i];
        __shared__ float red[256];
        red[threadIdx.x] = s;
        __syncthreads();
        for (int off = 128; off > 0; off >>= 1) {
            if (threadIdx.x < off) red[threadIdx.x] += red[threadIdx.x + off];
            __syncthreads();
        }
        if (threadIdx.x == 0) gc[row] = red[0] * (1.0f / 4096.0f);
    }
}

// ---------------- kernel 2: tiny attention path + ortho + stat zero ----------------
__global__ void k_attn(const float* __restrict__ gc, const float* __restrict__ proto,
                       const float* __restrict__ ctx_w, const float* __restrict__ ctx_b,
                       const float* __restrict__ wq, const float* __restrict__ bq,
                       const float* __restrict__ wk, const float* __restrict__ bk,
                       const float* __restrict__ wv, const float* __restrict__ bv,
                       const float* __restrict__ wo, const float* __restrict__ bo,
                       const float* __restrict__ lng, const float* __restrict__ lnb,
                       float* __restrict__ up, float* __restrict__ ortho, float* __restrict__ stats) {
    int t = threadIdx.x;
    __shared__ float seq[12][64], qs[12][64], ks_[12][64], vs[12][64], ao[12][64], rr[12][64];
    __shared__ float nr[NE], sq[NE * NE];

    if (blockIdx.x == 8) { // ortho + zero stats
        if (t < 22) stats[t] = 0.0f;
        if (t < NE) {
            float s = 0.f;
            for (int p = 0; p < NP; p++) { float v = proto[t * NP + p]; s += v * v; }
            nr[t] = rsqrtf(s);
        }
        __syncthreads();
        if (t < NE * NE) {
            int i = t / NE, j = t % NE;
            float d = 0.f;
            for (int p = 0; p < NP; p++) d += proto[i * NP + p] * proto[j * NP + p];
            float c = d * nr[i] * nr[j] - (i == j ? 1.0f : 0.0f);
            sq[t] = c * c;
        }
        __syncthreads();
        if (t == 0) {
            float s = 0.f;
            for (int i = 0; i < NE * NE; i++) s += sq[i];
            *ortho = sqrtf(s);
        }
        return;
    }

    int b = blockIdx.x;
    if (t < NP) {
        float a = ctx_b[t];
        for (int c = 0; c < NC; c++) a = fmaf(gc[b * NC + c], ctx_w[t * NC + c], a);
        seq[0][t] = a;
    }
    for (int i = t; i < NE * NP; i += 256) { int e = i >> 6, p = i & 63; seq[e + 1][p] = proto[e * NP + p]; }
    __syncthreads();
    for (int i = t; i < 12 * NP; i += 256) {
        int s = i >> 6, p = i & 63;
        float aq = bq[p], ak = bk[p], av = bv[p];
        for (int pp = 0; pp < NP; pp++) {
            float sv = seq[s][pp];
            aq = fmaf(sv, wq[p * NP + pp], aq);
            ak = fmaf(sv, wk[p * NP + pp], ak);
            av = fmaf(sv, wv[p * NP + pp], av);
        }
        qs[s][p] = aq; ks_[s][p] = ak; vs[s][p] = av;
    }
    __syncthreads();
    if (t < 48) {
        int h = t / 12, qq = t % 12;
        float sc[12], m = -1e30f;
        for (int kk = 0; kk < 12; kk++) {
            float s = 0.f;
            for (int d = 0; d < 16; d++) s = fmaf(qs[qq][h * 16 + d], ks_[kk][h * 16 + d], s);
            s *= 0.25f;
            sc[kk] = s;
            if (s > m) m = s;
        }
        float den = 0.f;
        for (int kk = 0; kk < 12; kk++) { sc[kk] = expf(sc[kk] - m); den += sc[kk]; }
        float inv = 1.0f / den;
        for (int d = 0; d < 16; d++) {
            float a = 0.f;
            for (int kk = 0; kk < 12; kk++) a = fmaf(sc[kk], vs[kk][h * 16 + d], a);
            ao[qq][h * 16 + d] = a * inv;
        }
    }
    __syncthreads();
    for (int i = t; i < 12 * NP; i += 256) {
        int s = i >> 6, p = i & 63;
        float a = bo[p];
        for (int pp = 0; pp < NP; pp++) a = fmaf(ao[s][pp], wo[p * NP + pp], a);
        rr[s][p] = a + seq[s][p];
    }
    __syncthreads();
    if (t < 12) {
        int s = t;
        float m = 0.f;
        for (int p = 0; p < NP; p++) m += rr[s][p];
        m *= (1.0f / 64.0f);
        float v = 0.f;
        for (int p = 0; p < NP; p++) { float d = rr[s][p] - m; v += d * d; }
        v *= (1.0f / 64.0f);
        float is = rsqrtf(v + 1e-5f);
        if (s >= 1)
            for (int p = 0; p < NP; p++)
                up[(b * NE + s - 1) * NP + p] = (rr[s][p] - m) * is * lng[p] + lnb[p];
    }
}

// ---------------- kernel 3: fused gating + MoE experts (8-wave blocks) ----------------
__global__ __launch_bounds__(512, 4) void k_main(
    const float* __restrict__ x, const float* __restrict__ inp_w, const float* __restrict__ inp_b,
    const unsigned short* __restrict__ ew1b, const float* __restrict__ eb1,
    const unsigned short* __restrict__ ew2b, const float* __restrict__ eb2,
    const float* __restrict__ upw, float* __restrict__ stats, float* __restrict__ out) {
    int tid = threadIdx.x;
    int bimg = blockIdx.x >> 6;
    int pix0 = (blockIdx.x & 63) << 6; // 64 pixels per block
    int wid = tid >> 6;                // 0..7
    int l15 = tid & 15;
    int l4 = (tid >> 4) & 3;

    // LDS map: xs @0 (16K) | hs0 @16384 (16K) | hs1 @32768 (16K, unioned with
    // phase-0 stage@32768(4K)+lpart@36864(11K)) | upl @49152 (2816) | wm @51968 (2816)
    __shared__ __align__(16) char smem[54784];
    char* xs = smem;
    float* stage = (float*)(smem + 32768);
    float* lpart = (float*)(smem + 36864);
    float* upl = (float*)(smem + 49152);
    float* wm = (float*)(smem + 51968);

    // ---- phase 0: stage x (fp32 + bf16 swizzled) and fp32 gating ----
    for (int i = tid; i < NE * NP; i += 512) upl[i] = upw[bimg * (NE * NP) + i];
    int pg = wid & 3;
    int pixl = tid & 63;
    float xr[16];
#pragma unroll
    for (int p = 0; p < 16; p++) xr[p] = inp_b[pg * 16 + p];

    for (int cb = 0; cb < NC; cb += 16) {
        for (int i = tid; i < 16 * 64; i += 512) {
            int cc = i >> 6, px = i & 63;
            float v = x[(size_t)(bimg * NC + cb + cc) * NHW + pix0 + px];
            stage[cc * 64 + px] = v;
            int off = ((px << 8) + ((cb + cc) << 1)) ^ ((px & 7) << 4);
            *(unsigned short*)(xs + off) = f2bf(v);
        }
        __syncthreads();
        if (tid < 256) {
#pragma unroll 4
            for (int cc = 0; cc < 16; cc++) {
                float xv = stage[cc * 64 + pixl];
#pragma unroll
                for (int p = 0; p < 16; p++)
                    xr[p] = fmaf(inp_w[(pg * 16 + p) * NC + cb + cc], xv, xr[p]);
            }
        }
        __syncthreads();
    }
    if (tid < 256) {
#pragma unroll
        for (int e = 0; e < NE; e++) {
            float a = 0.f;
#pragma unroll
            for (int p = 0; p < 16; p++) a = fmaf(upl[e * NP + pg * 16 + p], xr[p], a);
            lpart[(pg * NE + e) * 64 + pixl] = a;
        }
    }
    __syncthreads();

    // per-pixel softmax + top-6 (fp32 exact), stats via shuffle/ballot
    if (tid < 64) {
        float pr[NE];
        float mx = -1e30f;
#pragma unroll
        for (int e = 0; e < NE; e++) {
            float l = (lpart[(0 * NE + e) * 64 + tid] + lpart[(1 * NE + e) * 64 + tid] +
                       lpart[(2 * NE + e) * 64 + tid] + lpart[(3 * NE + e) * 64 + tid]) * 0.125f;
            pr[e] = l;
            mx = fmaxf(mx, l);
        }
        float den = 0.f;
#pragma unroll
        for (int e = 0; e < NE; e++) { pr[e] = __expf(pr[e] - mx); den += pr[e]; }
        float inv = 1.0f / den;
#pragma unroll
        for (int e = 0; e < NE; e++) pr[e] *= inv;
        unsigned used = 0;
        float tvsum = 0.f;
        for (int k = 0; k < 6; k++) { // strict > keeps lowest index on ties
            float bv = -1.f;
            int best = 0;
#pragma unroll
            for (int e = 0; e < NE; e++) {
                bool sel = !((used >> e) & 1) && (pr[e] > bv);
                bv = sel ? pr[e] : bv;
                best = sel ? e : best;
            }
            used |= 1u << best;
            tvsum += bv;
        }
        float itv = 1.0f / tvsum;
#pragma unroll
        for (int e = 0; e < NE; e++)
            wm[e * 64 + tid] = ((used >> e) & 1) ? pr[e] * itv : 0.0f;
#pragma unroll
        for (int e = 0; e < NE; e++) {
            float s = pr[e];
            for (int off = 32; off; off >>= 1) s += __shfl_xor(s, off);
            unsigned long long bal = __ballot((used >> e) & 1);
            if (tid == 0) {
                atomicAdd(&stats[e], s);
                atomicAdd(&stats[NE + e], (float)__popcll(bal));
            }
        }
    }
    __syncthreads();

    // ---- phase 1: experts, gate-weight folded into h; 1 barrier/chunk, dbuf hs ----
    f32x4 acc2[4];
#pragma unroll
    for (int nt = 0; nt < 4; nt++) acc2[nt] = {0.f, 0.f, 0.f, 0.f};

    for (int e = 0; e < NE; e++) {
#pragma unroll 2
        for (int j = 0; j < 4; j++) {
            char* hsbuf = (j & 1) ? (smem + 32768) : (smem + 16384);
            // layer-1 A fragments (bf16 weights, L2-resident)
            const unsigned short* w1p = ew1b + (size_t)(e * NHID + j * 128 + wid * 16 + l15) * NC;
            bf16x8 a1[4];
#pragma unroll
            for (int ksp = 0; ksp < 4; ksp++) a1[ksp] = *(const bf16x8*)(w1p + ksp * 32 + l4 * 8);
            f32x4 acc1[4];
#pragma unroll
            for (int nt = 0; nt < 4; nt++) acc1[nt] = {0.f, 0.f, 0.f, 0.f};
#pragma unroll
            for (int nt = 0; nt < 4; nt++)
#pragma unroll
                for (int ksp = 0; ksp < 4; ksp++) {
                    bf16x8 xb = ldsB(xs, nt * 16 + l15, ksp * 32 + l4 * 8);
                    acc1[nt] = __builtin_amdgcn_mfma_f32_16x16x32_bf16(a1[ksp], xb, acc1[nt], 0, 0, 0);
                }
            // prefetch layer-2 A fragments (hide L2 latency under gelu)
            const unsigned short* w2p = ew2b + (size_t)(e * NC + wid * 16 + l15) * NHID + j * 128;
            bf16x8 a2[4];
#pragma unroll
            for (int ksp = 0; ksp < 4; ksp++) a2[ksp] = *(const bf16x8*)(w2p + ksp * 32 + l4 * 8);
            // bias + gelu + gate-weight fold -> hs (bf16, swizzled)
            f32x4 b1 = *(const f32x4*)(eb1 + e * NHID + j * 128 + wid * 16 + l4 * 4);
            int oloc2 = (wid * 16 + l4 * 4) << 1;
#pragma unroll
            for (int nt = 0; nt < 4; nt++) {
                int px = nt * 16 + l15;
                float w = wm[e * 64 + px];
                bf16x4 hb;
#pragma unroll
                for (int r = 0; r < 4; r++) {
                    float v = acc1[nt][r] + b1[r];
                    hb[r] = (__bf16)(gelu_erf(v) * w);
                }
                int off = ((px << 8) + oloc2) ^ ((px & 7) << 4);
                *(uint2*)(hsbuf + off) = __builtin_bit_cast(uint2, hb);
            }
            __syncthreads(); // hs ready (WAR on hs[parity] guarded by previous chunk's barrier)
            // layer 2: acc2 accumulates across chunks AND experts (w folded into h)
#pragma unroll
            for (int nt = 0; nt < 4; nt++)
#pragma unroll
                for (int ksp = 0; ksp < 4; ksp++) {
                    bf16x8 hb2 = ldsB(hsbuf, nt * 16 + l15, ksp * 32 + l4 * 8);
                    acc2[nt] = __builtin_amdgcn_mfma_f32_16x16x32_bf16(a2[ksp], hb2, acc2[nt], 0, 0, 0);
                }
        }
    }

    // ---- epilogue: add sum_e w_e*eb2, then out = x + final ----
#pragma unroll
    for (int e = 0; e < NE; e++) {
        f32x4 b2 = *(const f32x4*)(eb2 + e * NC + wid * 16 + l4 * 4);
#pragma unroll
        for (int nt = 0; nt < 4; nt++) {
            float w = wm[e * 64 + nt * 16 + l15];
#pragma unroll
            for (int r = 0; r < 4; r++) acc2[nt][r] = fmaf(w, b2[r], acc2[nt][r]);
        }
    }
    int c0 = wid * 16 + l4 * 4;
#pragma unroll
    for (int nt = 0; nt < 4; nt++) {
        int px = pix0 + nt * 16 + l15;
#pragma unroll
        for (int r = 0; r < 4; r++) {
            size_t g = (size_t)(bimg * NC + c0 + r) * NHW + px;
            out[g] = x[g] + acc2[nt][r];
        }
    }
}

// ---------------- kernel 4: aux scalar ----------------
__global__ void k_final(const float* __restrict__ stats, const float* __restrict__ ortho,
                        float* __restrict__ out) {
    if (threadIdx.x == 0 && blockIdx.x == 0) {
        float aux = 0.f;
        for (int e = 0; e < NE; e++)
            aux += (stats[e] * (1.0f / 32768.0f)) * (stats[NE + e] * (1.0f / 32768.0f));
        aux *= (float)NE;
        out[4194304] = aux + 0.5f * (*ortho);
    }
}

extern "C" void kernel_launch(void* const* d_in, const int* in_sizes, int n_in,
                              void* d_out, int out_size, void* d_ws, size_t ws_size,
                              hipStream_t stream) {
    const float* x = (const float*)d_in[0];
    const float* proto = (const float*)d_in[1];
    const float* ctx_w = (const float*)d_in[2];
    const float* ctx_b = (const float*)d_in[3];
    const float* inp_w = (const float*)d_in[4];
    const float* inp_b = (const float*)d_in[5];
    const float* wq = (const float*)d_in[6];
    const float* bq = (const float*)d_in[7];
    const float* wk = (const float*)d_in[8];
    const float* bk = (const float*)d_in[9];
    const float* wv = (const float*)d_in[10];
    const float* bv = (const float*)d_in[11];
    const float* wo = (const float*)d_in[12];
    const float* bo = (const float*)d_in[13];
    const float* lng = (const float*)d_in[14];
    const float* lnb = (const float*)d_in[15];
    const float* ew1 = (const float*)d_in[16];
    const float* eb1 = (const float*)d_in[17];
    const float* ew2 = (const float*)d_in[18];
    const float* eb2 = (const float*)d_in[19];
    float* out = (float*)d_out;
    float* ws = (float*)d_ws;

    float* gc = ws;           // 1024 floats
    float* up = ws + 1024;    // 8*11*64 = 5632
    float* ortho = ws + 6656; // 1
    float* stats = ws + 6657; // 22
    unsigned short* ew1b = (unsigned short*)(ws + 8192); // 720896 ushorts
    unsigned short* ew2b = ew1b + NE * NHID * NC;        // 720896 ushorts

    k_prep<<<1536, 256, 0, stream>>>(ew1, ew2, ew1b, ew2b, x, gc);
    k_attn<<<9, 256, 0, stream>>>(gc, proto, ctx_w, ctx_b, wq, bq, wk, bk, wv, bv, wo, bo, lng, lnb,
                                  up, ortho, stats);
    k_main<<<512, 512, 0, stream>>>(x, inp_w, inp_b, ew1b, eb1, ew2b, eb2, up, stats, out);
    k_final<<<1, 64, 0, stream>>>(stats, ortho, out);
}